// Round 1
// baseline (143.350 us; speedup 1.0000x reference)
//
#include <hip/hip_runtime.h>
#include <math.h>

#define B_ 4
#define T_ 512
#define D_ 128
#define H_ 64
#define DEMO_ 12
#define LOG2E 1.4426950408889634f

// ---------------- kernel 1: Q = input@Wt ; K2T = (input@Wx + demo@Wd + bh)^T --
// block = 256 threads handles 8 consecutive (b,t) rows.
__global__ __launch_bounds__(256) void prep_kernel(
    const float* __restrict__ input, const float* __restrict__ demo,
    const float* __restrict__ Wt, const float* __restrict__ Wx,
    const float* __restrict__ Wd, const float* __restrict__ bh,
    float* __restrict__ Q, float* __restrict__ K2T)
{
    __shared__ float in_sh[8 * D_];
    int tid  = threadIdx.x;
    int row0 = blockIdx.x * 8;          // global row = b*T + t  (8 rows never straddle b)
    int b    = row0 >> 9;               // T_ == 512

    #pragma unroll
    for (int k = 0; k < 4; ++k)
        in_sh[tid + 256 * k] = input[row0 * D_ + tid + 256 * k];
    __syncthreads();

    int h  = tid & 63;
    int rr = tid >> 6;                  // 0..3 ; each thread does rows rr and rr+4

    // demo @ Wd + bh  (b is block-uniform -> scalarized loads)
    float dB = bh[h];
    #pragma unroll
    for (int kk = 0; kk < DEMO_; ++kk)
        dB = fmaf(demo[b * DEMO_ + kk], Wd[kk * H_ + h], dB);

    float q0 = 0.f, q1 = 0.f, x0 = 0.f, x1 = 0.f;
    #pragma unroll 8
    for (int k = 0; k < D_; ++k) {
        float wt = Wt[k * H_ + h];
        float wx = Wx[k * H_ + h];
        float a0 = in_sh[rr * D_ + k];
        float a1 = in_sh[(rr + 4) * D_ + k];
        q0 = fmaf(a0, wt, q0);
        q1 = fmaf(a1, wt, q1);
        x0 = fmaf(a0, wx, x0);
        x1 = fmaf(a1, wx, x1);
    }

    int ra = row0 + rr, rb = row0 + rr + 4;
    Q[ra * H_ + h] = q0;
    Q[rb * H_ + h] = q1;
    int ta = ra & (T_ - 1), tb = rb & (T_ - 1);
    K2T[(b * H_ + h) * T_ + ta] = x0 + dB;
    K2T[(b * H_ + h) * T_ + tb] = x1 + dB;
}

// ---------------- block-wide reductions (512 threads = 8 waves) --------------
__device__ __forceinline__ float block_max(float v, volatile float* red, int tid)
{
    #pragma unroll
    for (int off = 32; off; off >>= 1) v = fmaxf(v, __shfl_down(v, off, 64));
    if ((tid & 63) == 0) red[tid >> 6] = v;
    __syncthreads();
    if (tid == 0) {
        float m = red[0];
        #pragma unroll
        for (int w = 1; w < 8; ++w) m = fmaxf(m, red[w]);
        red[8] = m;
    }
    __syncthreads();
    float r = red[8];
    __syncthreads();
    return r;
}

__device__ __forceinline__ float block_sum(float v, volatile float* red, int tid)
{
    #pragma unroll
    for (int off = 32; off; off >>= 1) v += __shfl_down(v, off, 64);
    if ((tid & 63) == 0) red[tid >> 6] = v;
    __syncthreads();
    if (tid == 0) {
        float m = red[0];
        #pragma unroll
        for (int w = 1; w < 8; ++w) m += red[w];
        red[8] = m;
    }
    __syncthreads();
    float r = red[8];
    __syncthreads();
    return r;
}

// ---------------- kernel 2: scores + custom softmax + v ----------------------
// grid = (T/4, B); block = 512 threads; block handles query rows i0..i0+3.
__global__ __launch_bounds__(512, 4) void attn_kernel(
    const float* __restrict__ input,
    const float* __restrict__ Q, const float* __restrict__ K2T,
    const float* __restrict__ Wa, const float* __restrict__ ba,
    float* __restrict__ out_v, float* __restrict__ out_e)
{
    __shared__ float qsh[4 * H_];
    __shared__ float wash[H_];
    __shared__ float red[16];
    __shared__ float p_buf[4][T_];
    __shared__ float partial[4][4][D_];   // [s][g][d]

    int tid = threadIdx.x;
    int b   = blockIdx.y;
    int i0  = blockIdx.x * 4;

    if (tid < 4 * H_) qsh[tid] = Q[(b * T_ + i0) * H_ + tid];  // 4 rows contiguous
    if (tid < H_)     wash[tid] = Wa[tid];
    __syncthreads();

    int j = tid;
    // K2 row j, transposed layout -> coalesced dword loads
    float k2[H_];
    #pragma unroll
    for (int h = 0; h < H_; ++h)
        k2[h] = K2T[(b * H_ + h) * T_ + j];

    float ba0 = ba[0];
    float eg[4];
    #pragma unroll
    for (int g = 0; g < 4; ++g) eg[g] = ba0;

    // e[g][j] = ba + sum_h Wa[h] * tanh(Q[g][h] + K2[j][h])
    // tanh(x) = 1 - 2/(1 + exp2(2x*log2e))
    #pragma unroll
    for (int h = 0; h < H_; ++h) {
        float kv = k2[h];
        float wa = wash[h];
        #pragma unroll
        for (int g = 0; g < 4; ++g) {
            float t  = qsh[g * H_ + h] + kv;
            float ex = exp2f(t * (2.0f * LOG2E));
            float r  = __builtin_amdgcn_rcpf(1.0f + ex);
            float th = fmaf(-2.0f, r, 1.0f);
            eg[g]    = fmaf(wa, th, eg[g]);
        }
    }

    // custom softmax: rowmax over ALL j, exp, THEN causal mask, sum, /(s+1e-7)
    #pragma unroll 1
    for (int g = 0; g < 4; ++g) {
        float m = block_max(eg[g], red, tid);
        float p = exp2f((eg[g] - m) * LOG2E);
        if (j > i0 + g) p = 0.0f;
        float s = block_sum(p, red, tid);
        p *= __builtin_amdgcn_rcpf(s + 1e-7f);
        out_e[((size_t)(b * T_ + i0 + g)) * T_ + j] = p;
        p_buf[g][j] = p;
    }
    __syncthreads();

    // v[i_g, d] = sum_j p[g][j] * input[b, j, d] ; 4-way split over j
    int d  = tid & 127;
    int s4 = tid >> 7;                   // 0..3
    float acc[4] = {0.f, 0.f, 0.f, 0.f};
    #pragma unroll 4
    for (int jj = 0; jj < 128; ++jj) {
        int jx  = s4 * 128 + jj;
        float x = input[(b * T_ + jx) * D_ + d];
        #pragma unroll
        for (int g = 0; g < 4; ++g)
            acc[g] = fmaf(p_buf[g][jx], x, acc[g]);
    }
    #pragma unroll
    for (int g = 0; g < 4; ++g) partial[s4][g][d] = acc[g];
    __syncthreads();

    {
        int g  = tid >> 7;
        int dd = tid & 127;
        float v = partial[0][g][dd] + partial[1][g][dd]
                + partial[2][g][dd] + partial[3][g][dd];
        out_v[(b * T_ + i0 + g) * D_ + dd] = v;
    }
}

extern "C" void kernel_launch(void* const* d_in, const int* in_sizes, int n_in,
                              void* d_out, int out_size, void* d_ws, size_t ws_size,
                              hipStream_t stream)
{
    const float* input = (const float*)d_in[0];
    const float* demo  = (const float*)d_in[1];
    const float* Wt    = (const float*)d_in[2];
    const float* Wx    = (const float*)d_in[3];
    const float* Wd    = (const float*)d_in[4];
    const float* bh    = (const float*)d_in[5];
    const float* Wa    = (const float*)d_in[6];
    const float* ba    = (const float*)d_in[7];

    float* out_v = (float*)d_out;                     // [B,T,D]
    float* out_e = out_v + (size_t)B_ * T_ * D_;      // [B,T,T]

    float* Q   = (float*)d_ws;                        // [B*T, H]
    float* K2T = Q + (size_t)B_ * T_ * H_;            // [B, H, T]

    prep_kernel<<<dim3(B_ * T_ / 8), 256, 0, stream>>>(input, demo, Wt, Wx, Wd, bh, Q, K2T);
    attn_kernel<<<dim3(T_ / 4, B_), 512, 0, stream>>>(input, Q, K2T, Wa, ba, out_v, out_e);
}

// Round 2
// 117.479 us; speedup vs baseline: 1.2202x; 1.2202x over previous
//
#include <hip/hip_runtime.h>
#include <math.h>

#define B_ 4
#define T_ 512
#define D_ 128
#define H_ 64
#define DEMO_ 12
#define LOG2E 1.4426950408889634f

// ---------------- kernel 1: Q = input@Wt ; K2T = (input@Wx + demo@Wd + bh)^T --
// block = 256 threads handles 8 consecutive (b,t) rows.
__global__ __launch_bounds__(256) void prep_kernel(
    const float* __restrict__ input, const float* __restrict__ demo,
    const float* __restrict__ Wt, const float* __restrict__ Wx,
    const float* __restrict__ Wd, const float* __restrict__ bh,
    float* __restrict__ Q, float* __restrict__ K2T)
{
    __shared__ float in_sh[8 * D_];
    int tid  = threadIdx.x;
    int row0 = blockIdx.x * 8;          // global row = b*T + t  (8 rows never straddle b)
    int b    = row0 >> 9;               // T_ == 512

    #pragma unroll
    for (int k = 0; k < 4; ++k)
        in_sh[tid + 256 * k] = input[row0 * D_ + tid + 256 * k];
    __syncthreads();

    int h  = tid & 63;
    int rr = tid >> 6;                  // 0..3 ; each thread does rows rr and rr+4

    // demo @ Wd + bh  (b is block-uniform -> scalarized loads)
    float dB = bh[h];
    #pragma unroll
    for (int kk = 0; kk < DEMO_; ++kk)
        dB = fmaf(demo[b * DEMO_ + kk], Wd[kk * H_ + h], dB);

    float q0 = 0.f, q1 = 0.f, x0 = 0.f, x1 = 0.f;
    #pragma unroll 8
    for (int k = 0; k < D_; ++k) {
        float wt = Wt[k * H_ + h];
        float wx = Wx[k * H_ + h];
        float a0 = in_sh[rr * D_ + k];
        float a1 = in_sh[(rr + 4) * D_ + k];
        q0 = fmaf(a0, wt, q0);
        q1 = fmaf(a1, wt, q1);
        x0 = fmaf(a0, wx, x0);
        x1 = fmaf(a1, wx, x1);
    }

    int ra = row0 + rr, rb = row0 + rr + 4;
    Q[ra * H_ + h] = q0;
    Q[rb * H_ + h] = q1;
    int ta = ra & (T_ - 1), tb = rb & (T_ - 1);
    K2T[(b * H_ + h) * T_ + ta] = x0 + dB;
    K2T[(b * H_ + h) * T_ + tb] = x1 + dB;
}

// ---------------- block-wide reductions (512 threads = 8 waves) --------------
__device__ __forceinline__ float block_max(float v, volatile float* red, int tid)
{
    #pragma unroll
    for (int off = 32; off; off >>= 1) v = fmaxf(v, __shfl_down(v, off, 64));
    if ((tid & 63) == 0) red[tid >> 6] = v;
    __syncthreads();
    if (tid == 0) {
        float m = red[0];
        #pragma unroll
        for (int w = 1; w < 8; ++w) m = fmaxf(m, red[w]);
        red[8] = m;
    }
    __syncthreads();
    float r = red[8];
    __syncthreads();
    return r;
}

__device__ __forceinline__ float block_sum(float v, volatile float* red, int tid)
{
    #pragma unroll
    for (int off = 32; off; off >>= 1) v += __shfl_down(v, off, 64);
    if ((tid & 63) == 0) red[tid >> 6] = v;
    __syncthreads();
    if (tid == 0) {
        float m = red[0];
        #pragma unroll
        for (int w = 1; w < 8; ++w) m += red[w];
        red[8] = m;
    }
    __syncthreads();
    float r = red[8];
    __syncthreads();
    return r;
}

// ---------------- kernel 2: scores + custom softmax + v ----------------------
// grid = (T/4, B); block = 512 threads; block handles query rows i0..i0+3.
// NO per-thread K2 array (it spilled to scratch in R1 -> 240 MB HBM traffic).
// K2T is streamed from global in 8-wide h-chunks; K2T is 512 KB -> L2-resident.
__global__ __launch_bounds__(512, 4) void attn_kernel(
    const float* __restrict__ input,
    const float* __restrict__ Q, const float* __restrict__ K2T,
    const float* __restrict__ Wa, const float* __restrict__ ba,
    float* __restrict__ out_v, float* __restrict__ out_e)
{
    __shared__ float qsh[4 * H_];
    __shared__ float wash[H_];
    __shared__ float red[16];
    __shared__ float p_buf[4][T_];
    __shared__ float partial[4][4][D_];   // [s][g][d]

    int tid = threadIdx.x;
    int b   = blockIdx.y;
    int i0  = blockIdx.x * 4;

    if (tid < 4 * H_) qsh[tid] = Q[(b * T_ + i0) * H_ + tid];  // 4 rows contiguous
    if (tid < H_)     wash[tid] = Wa[tid];
    __syncthreads();

    int j = tid;
    const float* k2p = K2T + (size_t)(b * H_) * T_ + j;

    float ba0 = ba[0];
    float eg[4];
    #pragma unroll
    for (int g = 0; g < 4; ++g) eg[g] = ba0;

    // e[g][j] = ba + sum_h Wa[h] * tanh(Q[g][h] + K2[j][h])
    // tanh(x) = 1 - 2/(1 + exp2(2x*log2e))
    #pragma unroll 2
    for (int h0 = 0; h0 < H_; h0 += 8) {
        float kv[8];
        #pragma unroll
        for (int u = 0; u < 8; ++u)
            kv[u] = k2p[(size_t)(h0 + u) * T_];
        #pragma unroll
        for (int u = 0; u < 8; ++u) {
            int h    = h0 + u;
            float wa = wash[h];
            #pragma unroll
            for (int g = 0; g < 4; ++g) {
                float t  = qsh[g * H_ + h] + kv[u];
                float ex = exp2f(t * (2.0f * LOG2E));
                float r  = __builtin_amdgcn_rcpf(1.0f + ex);
                float th = fmaf(-2.0f, r, 1.0f);
                eg[g]    = fmaf(wa, th, eg[g]);
            }
        }
    }

    // custom softmax: rowmax over ALL j, exp, THEN causal mask, sum, /(s+1e-7)
    #pragma unroll 1
    for (int g = 0; g < 4; ++g) {
        float m = block_max(eg[g], red, tid);
        float p = exp2f((eg[g] - m) * LOG2E);
        if (j > i0 + g) p = 0.0f;
        float s = block_sum(p, red, tid);
        p *= __builtin_amdgcn_rcpf(s + 1e-7f);
        out_e[((size_t)(b * T_ + i0 + g)) * T_ + j] = p;
        p_buf[g][j] = p;
    }
    __syncthreads();

    // v[i_g, d] = sum_j p[g][j] * input[b, j, d] ; 4-way split over j
    int d  = tid & 127;
    int s4 = tid >> 7;                   // 0..3
    float acc[4] = {0.f, 0.f, 0.f, 0.f};
    #pragma unroll 4
    for (int jj = 0; jj < 128; ++jj) {
        int jx  = s4 * 128 + jj;
        float x = input[(b * T_ + jx) * D_ + d];
        #pragma unroll
        for (int g = 0; g < 4; ++g)
            acc[g] = fmaf(p_buf[g][jx], x, acc[g]);
    }
    #pragma unroll
    for (int g = 0; g < 4; ++g) partial[s4][g][d] = acc[g];
    __syncthreads();

    {
        int g  = tid >> 7;
        int dd = tid & 127;
        float v = partial[0][g][dd] + partial[1][g][dd]
                + partial[2][g][dd] + partial[3][g][dd];
        out_v[(b * T_ + i0 + g) * D_ + dd] = v;
    }
}

extern "C" void kernel_launch(void* const* d_in, const int* in_sizes, int n_in,
                              void* d_out, int out_size, void* d_ws, size_t ws_size,
                              hipStream_t stream)
{
    const float* input = (const float*)d_in[0];
    const float* demo  = (const float*)d_in[1];
    const float* Wt    = (const float*)d_in[2];
    const float* Wx    = (const float*)d_in[3];
    const float* Wd    = (const float*)d_in[4];
    const float* bh    = (const float*)d_in[5];
    const float* Wa    = (const float*)d_in[6];
    const float* ba    = (const float*)d_in[7];

    float* out_v = (float*)d_out;                     // [B,T,D]
    float* out_e = out_v + (size_t)B_ * T_ * D_;      // [B,T,T]

    float* Q   = (float*)d_ws;                        // [B*T, H]
    float* K2T = Q + (size_t)B_ * T_ * H_;            // [B, H, T]

    prep_kernel<<<dim3(B_ * T_ / 8), 256, 0, stream>>>(input, demo, Wt, Wx, Wd, bh, Q, K2T);
    attn_kernel<<<dim3(T_ / 4, B_), 512, 0, stream>>>(input, Q, K2T, Wa, ba, out_v, out_e);
}

// Round 3
// 102.702 us; speedup vs baseline: 1.3958x; 1.1439x over previous
//
#include <hip/hip_runtime.h>
#include <math.h>

#define B_ 4
#define T_ 512
#define D_ 128
#define H_ 64
#define DEMO_ 12
#define LOG2E 1.4426950408889634f
#define SC2   (2.0f * LOG2E)          // fold the tanh 2x and the exp2 conversion

typedef float float4v __attribute__((ext_vector_type(4)));

// ---------------- kernel 1: Q' = (input@Wt)*SC2 ; K2T' = ((input@Wx)+demo@Wd+bh)*SC2 ^T
// block = 256 threads handles 8 consecutive (b,t) rows.
__global__ __launch_bounds__(256) void prep_kernel(
    const float* __restrict__ input, const float* __restrict__ demo,
    const float* __restrict__ Wt, const float* __restrict__ Wx,
    const float* __restrict__ Wd, const float* __restrict__ bh,
    float* __restrict__ Q, float* __restrict__ K2T)
{
    __shared__ float in_sh[8 * D_];
    int tid  = threadIdx.x;
    int row0 = blockIdx.x * 8;          // global row = b*T + t (8 rows never straddle b)
    int b    = row0 >> 9;               // T_ == 512

    #pragma unroll
    for (int k = 0; k < 4; ++k)
        in_sh[tid + 256 * k] = input[row0 * D_ + tid + 256 * k];
    __syncthreads();

    int h  = tid & 63;
    int rr = tid >> 6;                  // 0..3 ; each thread does rows rr and rr+4

    float dB = bh[h];
    #pragma unroll
    for (int kk = 0; kk < DEMO_; ++kk)
        dB = fmaf(demo[b * DEMO_ + kk], Wd[kk * H_ + h], dB);

    float q0 = 0.f, q1 = 0.f, x0 = 0.f, x1 = 0.f;
    #pragma unroll 8
    for (int k = 0; k < D_; ++k) {
        float wt = Wt[k * H_ + h];
        float wx = Wx[k * H_ + h];
        float a0 = in_sh[rr * D_ + k];
        float a1 = in_sh[(rr + 4) * D_ + k];
        q0 = fmaf(a0, wt, q0);
        q1 = fmaf(a1, wt, q1);
        x0 = fmaf(a0, wx, x0);
        x1 = fmaf(a1, wx, x1);
    }

    int ra = row0 + rr, rb = row0 + rr + 4;
    Q[ra * H_ + h] = q0 * SC2;
    Q[rb * H_ + h] = q1 * SC2;
    int ta = ra & (T_ - 1), tb = rb & (T_ - 1);
    K2T[(b * H_ + h) * T_ + ta] = (x0 + dB) * SC2;
    K2T[(b * H_ + h) * T_ + tb] = (x1 + dB) * SC2;
}

// ---------------- kernel 2: scores + custom softmax + v ----------------------
// grid = (T/4, B); block = 512 threads (8 waves); block owns query rows i0..i0+3.
// Inner loop floor: add, exp2, add, rcp, fma per tanh-element (Wa via s_load,
// q via one ds_read_b128 per h). 4 barriers total (was 24 in R2).
__global__ __launch_bounds__(512, 4) void attn_kernel(
    const float* __restrict__ input,
    const float* __restrict__ Qs, const float* __restrict__ K2T,
    const float* __restrict__ Wa, const float* __restrict__ ba,
    float* __restrict__ out_v, float* __restrict__ out_e)
{
    __shared__ float qsh[H_ * 4];         // [h][g]
    __shared__ float red_m[8 * 4];        // [wave][g]
    __shared__ float red_s[8 * 4];        // [wave][g]
    __shared__ float csh;                 // (ba + sum Wa) * LOG2E
    __shared__ float p_sh[T_ * 4];        // [j][g]  (unnormalized, masked)
    __shared__ float partial[4][4 * D_];  // [s4][g*128+d] (normalized)

    int tid  = threadIdx.x;
    int b    = blockIdx.y;
    int i0   = blockIdx.x * 4;
    int lane = tid & 63, wv = tid >> 6;

    if (tid < 256) {                      // qsh[h*4+g] = Q'[(i0+g), h]
        int h = tid >> 2, g = tid & 3;
        qsh[tid] = Qs[(size_t)(b * T_ + i0 + g) * H_ + h];
    }
    if (tid < 64) {                       // C = (ba + sum Wa) * LOG2E via wave 0
        float w = Wa[tid];
        #pragma unroll
        for (int off = 32; off; off >>= 1) w += __shfl_down(w, off, 64);
        if (tid == 0) csh = (ba[0] + w) * LOG2E;
    }
    __syncthreads();                      // B1

    const int j = tid;
    const float* k2p = K2T + (size_t)b * H_ * T_ + j;

    // acc[g] = sum_h Wa[h] / (1 + exp(2*(q+k2)))      (r = (1-tanh)/2)
    float acc[4] = {0.f, 0.f, 0.f, 0.f};
    #pragma unroll 2
    for (int h0 = 0; h0 < H_; h0 += 8) {
        float kv[8];
        #pragma unroll
        for (int u = 0; u < 8; ++u)
            kv[u] = k2p[(size_t)(h0 + u) * T_];
        #pragma unroll
        for (int u = 0; u < 8; ++u) {
            int h    = h0 + u;
            float wa = Wa[h];                            // uniform -> s_load
            float4v q4 = *(const float4v*)&qsh[h * 4];   // ds_read_b128
            #pragma unroll
            for (int g = 0; g < 4; ++g) {
                float ex = __builtin_amdgcn_exp2f(q4[g] + kv[u]);
                float r  = __builtin_amdgcn_rcpf(1.0f + ex);
                acc[g]   = fmaf(wa, r, acc[g]);
            }
        }
    }

    // eg (already scaled by LOG2E): eg = CL - 2*LOG2E*acc
    float CL = csh;
    float eg[4], M[4], p[4], S[4];
    #pragma unroll
    for (int g = 0; g < 4; ++g) {
        eg[g] = fmaf(-2.0f * LOG2E, acc[g], CL);
        M[g]  = eg[g];
    }

    // block max over ALL j (pre-mask, per reference) — 4 interleaved chains
    #pragma unroll
    for (int off = 32; off; off >>= 1) {
        #pragma unroll
        for (int g = 0; g < 4; ++g) M[g] = fmaxf(M[g], __shfl_down(M[g], off, 64));
    }
    if (lane == 0) ((float4v*)red_m)[wv] = (float4v){M[0], M[1], M[2], M[3]};
    __syncthreads();                      // B2
    {
        float4v r0 = ((float4v*)red_m)[0];
        #pragma unroll
        for (int w = 1; w < 8; ++w) {
            float4v rw = ((float4v*)red_m)[w];
            #pragma unroll
            for (int g = 0; g < 4; ++g) r0[g] = fmaxf(r0[g], rw[g]);
        }
        #pragma unroll
        for (int g = 0; g < 4; ++g) M[g] = r0[g];
    }

    // p = exp2(eg - M); mask AFTER exp (custom softmax); stash + wave-sum
    #pragma unroll
    for (int g = 0; g < 4; ++g) {
        p[g] = __builtin_amdgcn_exp2f(eg[g] - M[g]);
        if (j > i0 + g) p[g] = 0.0f;
        S[g] = p[g];
    }
    *(float4v*)&p_sh[j * 4] = (float4v){p[0], p[1], p[2], p[3]};
    #pragma unroll
    for (int off = 32; off; off >>= 1) {
        #pragma unroll
        for (int g = 0; g < 4; ++g) S[g] += __shfl_down(S[g], off, 64);
    }
    if (lane == 0) ((float4v*)red_s)[wv] = (float4v){S[0], S[1], S[2], S[3]};
    __syncthreads();                      // B3 (covers red_s and p_sh)
    float inv_s[4];
    {
        float4v r0 = ((float4v*)red_s)[0];
        #pragma unroll
        for (int w = 1; w < 8; ++w) {
            float4v rw = ((float4v*)red_s)[w];
            #pragma unroll
            for (int g = 0; g < 4; ++g) r0[g] += rw[g];
        }
        #pragma unroll
        for (int g = 0; g < 4; ++g) inv_s[g] = __builtin_amdgcn_rcpf(r0[g] + 1e-7f);
    }

    // write normalized e (coalesced per g)
    #pragma unroll
    for (int g = 0; g < 4; ++g)
        out_e[((size_t)(b * T_ + i0 + g)) * T_ + j] = p[g] * inv_s[g];

    // v[i_g, d] = inv_s * sum_j p[j]*input[b,j,d] ; 4-way split over j
    {
        int d  = tid & 127;
        int s4 = tid >> 7;
        const float* inp = input + ((size_t)(b * T_) + s4 * 128) * D_ + d;
        float va[4] = {0.f, 0.f, 0.f, 0.f};
        #pragma unroll 4
        for (int jj = 0; jj < 128; ++jj) {
            float x = inp[(size_t)jj * D_];
            float4v p4 = *(const float4v*)&p_sh[(s4 * 128 + jj) * 4];
            #pragma unroll
            for (int g = 0; g < 4; ++g) va[g] = fmaf(p4[g], x, va[g]);
        }
        #pragma unroll
        for (int g = 0; g < 4; ++g)
            partial[s4][g * D_ + d] = va[g] * inv_s[g];
    }
    __syncthreads();                      // B4

    {
        int g  = tid >> 7;
        int dd = tid & 127;
        float v = partial[0][g * D_ + dd] + partial[1][g * D_ + dd]
                + partial[2][g * D_ + dd] + partial[3][g * D_ + dd];
        out_v[(size_t)(b * T_ + i0 + g) * D_ + dd] = v;
    }
}

extern "C" void kernel_launch(void* const* d_in, const int* in_sizes, int n_in,
                              void* d_out, int out_size, void* d_ws, size_t ws_size,
                              hipStream_t stream)
{
    const float* input = (const float*)d_in[0];
    const float* demo  = (const float*)d_in[1];
    const float* Wt    = (const float*)d_in[2];
    const float* Wx    = (const float*)d_in[3];
    const float* Wd    = (const float*)d_in[4];
    const float* bh    = (const float*)d_in[5];
    const float* Wa    = (const float*)d_in[6];
    const float* ba    = (const float*)d_in[7];

    float* out_v = (float*)d_out;                     // [B,T,D]
    float* out_e = out_v + (size_t)B_ * T_ * D_;      // [B,T,T]

    float* Q   = (float*)d_ws;                        // [B*T, H]  (pre-scaled)
    float* K2T = Q + (size_t)B_ * T_ * H_;            // [B, H, T] (pre-scaled)

    prep_kernel<<<dim3(B_ * T_ / 8), 256, 0, stream>>>(input, demo, Wt, Wx, Wd, bh, Q, K2T);
    attn_kernel<<<dim3(T_ / 4, B_), 512, 0, stream>>>(input, Q, K2T, Wa, ba, out_v, out_e);
}

// Round 4
// 99.162 us; speedup vs baseline: 1.4456x; 1.0357x over previous
//
#include <hip/hip_runtime.h>
#include <math.h>

#define B_ 4
#define T_ 512
#define D_ 128
#define H_ 64
#define DEMO_ 12
#define LOG2E 1.4426950408889634f
#define SC2   (2.0f * LOG2E)          // fold the tanh 2x and the exp2 conversion

typedef float float4v __attribute__((ext_vector_type(4)));
typedef float float2v __attribute__((ext_vector_type(2)));

// ---------------- kernel 1: Q' = (input@Wt)*SC2 ; K2T' = ((input@Wx)+demo@Wd+bh)*SC2 ^T
// block = 256 threads handles 8 consecutive (b,t) rows.
__global__ __launch_bounds__(256) void prep_kernel(
    const float* __restrict__ input, const float* __restrict__ demo,
    const float* __restrict__ Wt, const float* __restrict__ Wx,
    const float* __restrict__ Wd, const float* __restrict__ bh,
    float* __restrict__ Q, float* __restrict__ K2T)
{
    __shared__ float in_sh[8 * D_];
    int tid  = threadIdx.x;
    int row0 = blockIdx.x * 8;          // global row = b*T + t (8 rows never straddle b)
    int b    = row0 >> 9;               // T_ == 512

    #pragma unroll
    for (int k = 0; k < 4; ++k)
        in_sh[tid + 256 * k] = input[row0 * D_ + tid + 256 * k];
    __syncthreads();

    int h  = tid & 63;
    int rr = tid >> 6;                  // 0..3 ; each thread does rows rr and rr+4

    float dB = bh[h];
    #pragma unroll
    for (int kk = 0; kk < DEMO_; ++kk)
        dB = fmaf(demo[b * DEMO_ + kk], Wd[kk * H_ + h], dB);

    float q0 = 0.f, q1 = 0.f, x0 = 0.f, x1 = 0.f;
    #pragma unroll 8
    for (int k = 0; k < D_; ++k) {
        float wt = Wt[k * H_ + h];
        float wx = Wx[k * H_ + h];
        float a0 = in_sh[rr * D_ + k];
        float a1 = in_sh[(rr + 4) * D_ + k];
        q0 = fmaf(a0, wt, q0);
        q1 = fmaf(a1, wt, q1);
        x0 = fmaf(a0, wx, x0);
        x1 = fmaf(a1, wx, x1);
    }

    int ra = row0 + rr, rb = row0 + rr + 4;
    Q[ra * H_ + h] = q0 * SC2;
    Q[rb * H_ + h] = q1 * SC2;
    int ta = ra & (T_ - 1), tb = rb & (T_ - 1);
    K2T[(b * H_ + h) * T_ + ta] = (x0 + dB) * SC2;
    K2T[(b * H_ + h) * T_ + tb] = (x1 + dB) * SC2;
}

// ---------------- kernel 2: scores + custom softmax + v ----------------------
// grid = (T/4, B); block = 1024 threads (16 waves). Block owns query rows
// i0..i0+3; half u = tid>>9 handles rows {2u, 2u+1} for j = tid&511.
// 2 blocks/CU -> 32 waves/CU -> 8 waves/SIMD (R3 had only 4: latency-bound).
__global__ __launch_bounds__(1024, 8) void attn_kernel(
    const float* __restrict__ input,
    const float* __restrict__ Qs, const float* __restrict__ K2T,
    const float* __restrict__ Wa, const float* __restrict__ ba,
    float* __restrict__ out_v, float* __restrict__ out_e)
{
    __shared__ float qsh[H_ * 4];         // [h][g]
    __shared__ float red_m[16 * 2];       // [wave][local g]
    __shared__ float red_s[16 * 2];       // [wave][local g]
    __shared__ float csh;                 // (ba + sum Wa) * LOG2E
    __shared__ float p_sh[T_ * 4];        // [j][g]  (unnormalized, masked)
    __shared__ float partial[8][4 * D_];  // [s8][g*128+d] (unnormalized)

    int tid  = threadIdx.x;
    int b    = blockIdx.y;
    int i0   = blockIdx.x * 4;
    int lane = tid & 63, wv = tid >> 6;
    int j    = tid & (T_ - 1);
    int u    = tid >> 9;                  // 0/1 -> rows {0,1} or {2,3}
    int g0   = 2 * u;

    if (tid < 256) {                      // qsh[h*4+g] = Q'[(i0+g), h]
        int h = tid >> 2, g = tid & 3;
        qsh[tid] = Qs[(size_t)(b * T_ + i0 + g) * H_ + h];
    }
    if (tid < 64) {                       // C = (ba + sum Wa) * LOG2E via wave 0
        float w = Wa[tid];
        #pragma unroll
        for (int off = 32; off; off >>= 1) w += __shfl_down(w, off, 64);
        if (tid == 0) csh = (ba[0] + w) * LOG2E;
    }
    __syncthreads();                      // B1

    const float* k2p = K2T + (size_t)b * H_ * T_ + j;

    // acc[g] = sum_h Wa[h] / (1 + exp(2*(q+k2)))      (r = (1-tanh)/2)
    float acc0 = 0.f, acc1 = 0.f;
    #pragma unroll 2
    for (int h0 = 0; h0 < H_; h0 += 8) {
        float kv[8];
        #pragma unroll
        for (int uu = 0; uu < 8; ++uu)
            kv[uu] = k2p[(size_t)(h0 + uu) * T_];
        #pragma unroll
        for (int uu = 0; uu < 8; ++uu) {
            int h    = h0 + uu;
            float wa = Wa[h];                              // uniform -> s_load
            float2v q2 = *(const float2v*)&qsh[h * 4 + g0];// ds_read_b64 bcast
            float ex0 = __builtin_amdgcn_exp2f(q2[0] + kv[uu]);
            float ex1 = __builtin_amdgcn_exp2f(q2[1] + kv[uu]);
            acc0 = fmaf(wa, __builtin_amdgcn_rcpf(1.0f + ex0), acc0);
            acc1 = fmaf(wa, __builtin_amdgcn_rcpf(1.0f + ex1), acc1);
        }
    }

    // eg (already scaled by LOG2E): eg = CL - 2*LOG2E*acc
    float CL  = csh;
    float eg0 = fmaf(-2.0f * LOG2E, acc0, CL);
    float eg1 = fmaf(-2.0f * LOG2E, acc1, CL);

    // block max over ALL j (pre-mask, per reference), per u-half
    float M0 = eg0, M1 = eg1;
    #pragma unroll
    for (int off = 32; off; off >>= 1) {
        M0 = fmaxf(M0, __shfl_down(M0, off, 64));
        M1 = fmaxf(M1, __shfl_down(M1, off, 64));
    }
    if (lane == 0) ((float2v*)red_m)[wv] = (float2v){M0, M1};
    __syncthreads();                      // B2
    {
        float2v m = ((float2v*)red_m)[u * 8];
        #pragma unroll
        for (int w = 1; w < 8; ++w) {
            float2v mw = ((float2v*)red_m)[u * 8 + w];
            m[0] = fmaxf(m[0], mw[0]);
            m[1] = fmaxf(m[1], mw[1]);
        }
        M0 = m[0]; M1 = m[1];
    }

    // p = exp2(eg - M); mask AFTER exp (custom softmax); stash + wave-sum
    float p0 = __builtin_amdgcn_exp2f(eg0 - M0);
    float p1 = __builtin_amdgcn_exp2f(eg1 - M1);
    if (j > i0 + g0)     p0 = 0.0f;
    if (j > i0 + g0 + 1) p1 = 0.0f;
    *(float2v*)&p_sh[j * 4 + g0] = (float2v){p0, p1};
    float S0 = p0, S1 = p1;
    #pragma unroll
    for (int off = 32; off; off >>= 1) {
        S0 += __shfl_down(S0, off, 64);
        S1 += __shfl_down(S1, off, 64);
    }
    if (lane == 0) ((float2v*)red_s)[wv] = (float2v){S0, S1};
    __syncthreads();                      // B3 (covers red_s and p_sh)

    float inv4[4];
    {
        float2v a = ((float2v*)red_s)[0];
        float2v c = ((float2v*)red_s)[8];
        #pragma unroll
        for (int w = 1; w < 8; ++w) {
            float2v aw = ((float2v*)red_s)[w];
            float2v cw = ((float2v*)red_s)[8 + w];
            a[0] += aw[0]; a[1] += aw[1];
            c[0] += cw[0]; c[1] += cw[1];
        }
        inv4[0] = __builtin_amdgcn_rcpf(a[0] + 1e-7f);
        inv4[1] = __builtin_amdgcn_rcpf(a[1] + 1e-7f);
        inv4[2] = __builtin_amdgcn_rcpf(c[0] + 1e-7f);
        inv4[3] = __builtin_amdgcn_rcpf(c[1] + 1e-7f);
    }

    // write normalized e (each half writes its 2 rows, coalesced)
    out_e[((size_t)(b * T_ + i0 + g0))     * T_ + j] = p0 * inv4[g0];
    out_e[((size_t)(b * T_ + i0 + g0 + 1)) * T_ + j] = p1 * inv4[g0 + 1];

    // v[i_g, d] = inv_s * sum_j p[j]*input[b,j,d] ; 8-way split over j
    {
        int d  = tid & 127;
        int s8 = tid >> 7;               // 0..7
        const float* inp = input + ((size_t)(b * T_) + s8 * 64) * D_ + d;
        float va[4] = {0.f, 0.f, 0.f, 0.f};
        #pragma unroll 4
        for (int jj = 0; jj < 64; ++jj) {
            float x = inp[(size_t)jj * D_];
            float4v p4 = *(const float4v*)&p_sh[(s8 * 64 + jj) * 4];
            #pragma unroll
            for (int g = 0; g < 4; ++g) va[g] = fmaf(p4[g], x, va[g]);
        }
        #pragma unroll
        for (int g = 0; g < 4; ++g)
            partial[s8][g * D_ + d] = va[g] * inv4[g];
    }
    __syncthreads();                      // B4

    if (tid < 512) {
        int g  = tid >> 7;
        int dd = tid & 127;
        float v = 0.f;
        #pragma unroll
        for (int s = 0; s < 8; ++s) v += partial[s][g * D_ + dd];
        out_v[(size_t)(b * T_ + i0 + g) * D_ + dd] = v;
    }
}

extern "C" void kernel_launch(void* const* d_in, const int* in_sizes, int n_in,
                              void* d_out, int out_size, void* d_ws, size_t ws_size,
                              hipStream_t stream)
{
    const float* input = (const float*)d_in[0];
    const float* demo  = (const float*)d_in[1];
    const float* Wt    = (const float*)d_in[2];
    const float* Wx    = (const float*)d_in[3];
    const float* Wd    = (const float*)d_in[4];
    const float* bh    = (const float*)d_in[5];
    const float* Wa    = (const float*)d_in[6];
    const float* ba    = (const float*)d_in[7];

    float* out_v = (float*)d_out;                     // [B,T,D]
    float* out_e = out_v + (size_t)B_ * T_ * D_;      // [B,T,T]

    float* Q   = (float*)d_ws;                        // [B*T, H]  (pre-scaled)
    float* K2T = Q + (size_t)B_ * T_ * H_;            // [B, H, T] (pre-scaled)

    prep_kernel<<<dim3(B_ * T_ / 8), 256, 0, stream>>>(input, demo, Wt, Wx, Wd, bh, Q, K2T);
    attn_kernel<<<dim3(T_ / 4, B_), 1024, 0, stream>>>(input, Q, K2T, Wa, ba, out_v, out_e);
}